// Round 10
// baseline (316.706 us; speedup 1.0000x reference)
//
#include <hip/hip_runtime.h>
#include <math.h>

typedef _Float16 f16_t;
typedef _Float16 f16x8 __attribute__((ext_vector_type(8)));
typedef _Float16 f16x4 __attribute__((ext_vector_type(4)));
typedef _Float16 f16x2 __attribute__((ext_vector_type(2)));
typedef __fp16 h16x2 __attribute__((ext_vector_type(2)));
typedef float f32x16 __attribute__((ext_vector_type(16)));

// fp32 -> fp16 weights in 32x32x16-MFMA A-fragment-linear order:
// A-frag element (ks, nt, lane, j) = W[nt*32 + (lane&31)][ks*16 + (lane>>5)*8 + j]
// at ((ks*8 + nt)*64 + lane)*8 + j  -> per-wave frag load = contiguous 16 B/lane.
// W1 (8 nt x 8 ks) at 0 (32768 elems); W2 (8 nt x 16 ks) at 32768 (65536 elems).
__global__ void wconv(const float* __restrict__ W1, const float* __restrict__ W2,
                      f16_t* __restrict__ o) {
  int i = blockIdx.x * 256 + threadIdx.x;  // 0..65535
  if (i < 32768) {
    int n = i >> 7, k = i & 127;
    int nt = n >> 5, ln = n & 31;
    int ks = k >> 4, hi = (k >> 3) & 1, j = k & 7;
    o[((ks * 8 + nt) * 64 + hi * 32 + ln) * 8 + j] = (f16_t)W1[i];
  }
  {
    int n = i >> 8, k = i & 255;
    int nt = n >> 5, ln = n & 31;
    int ks = k >> 4, hi = (k >> 3) & 1, j = k & 7;
    o[32768 + ((ks * 8 + nt) * 64 + hi * 32 + ln) * 8 + j] = (f16_t)W2[i];
  }
}

// h fp32 -> fp16 (8 elems/thread)
__global__ void hconv(const float* __restrict__ h, f16_t* __restrict__ hf, int n8) {
  int i = blockIdx.x * 256 + threadIdx.x;
  if (i < n8) {
    const float4 a = *(const float4*)(h + i * 8);
    const float4 b = *(const float4*)(h + i * 8 + 4);
    f16x8 v;
    v[0] = (f16_t)a.x; v[1] = (f16_t)a.y; v[2] = (f16_t)a.z; v[3] = (f16_t)a.w;
    v[4] = (f16_t)b.x; v[5] = (f16_t)b.y; v[6] = (f16_t)b.z; v[7] = (f16_t)b.w;
    *(f16x8*)(hf + i * 8) = v;
  }
}

__device__ __forceinline__ f16x2 pk2(float a, float b) {
  union { h16x2 h; f16x2 f; } u;
  u.h = __builtin_amdgcn_cvt_pkrtz(a, b);
  return u.f;
}

#define COMP(v, r) ((r) == 0 ? (v).x : (r) == 1 ? (v).y : (r) == 2 ? (v).z : (v).w)

// Transposed fused MLP with 32x32x16 MFMA: D[feat][edge] = W @ x^T.
// Tile = 128 edges, 512 threads, 8 waves = 4 feat-rows (64 f) x 2 edge-cols (64 e);
// wave tile 64f x 64e = acc[2][2] of f32x16 (64 regs, AGPR). Weights stream
// global(L2)->VGPR fragment-linear; x LDS-stationary; static 64 KB; 7 barriers.
__global__ __launch_bounds__(512, 2) void fused_mlp(
    const float* __restrict__ h,
    const f16_t* __restrict__ hf, int use_hf,
    const int* __restrict__ src,
    const int* __restrict__ dst,
    const f16_t* __restrict__ wks,
    const float* __restrict__ b1, const float* __restrict__ g1, const float* __restrict__ be1,
    const float* __restrict__ b2, const float* __restrict__ g2, const float* __restrict__ be2,
    const float* __restrict__ w3, const float* __restrict__ b3,
    float* __restrict__ out, int E, int nrows) {
  __shared__ __attribute__((aligned(16))) f16_t xbuf[32768];  // 64 KB exactly
  // LN1 stats in upper quarter (x0 occupies lower 32 KB only):
  float* s1sum = (float*)(xbuf + 24576);        // [4][128]
  float* s1sq  = (float*)(xbuf + 24576) + 512;  // [4][128]
  // LN2 stats + p at base (x1 dead after GEMM2 barrier):
  float* s2sum = (float*)xbuf;          // [4][128]
  float* s2sq  = (float*)xbuf + 512;    // [4][128]
  float* pbuf  = (float*)xbuf + 1024;   // [4][128]

  const int t = threadIdx.x;
  const int ebase = blockIdx.x * 128;

  // ---------- gather: x0[m][k] = h[src][k]*h[dst][k], fp16, swizzled stride-128 ----------
  {
    const int m = t >> 2;          // edge 0..127
    const int kq = (t & 3) * 32;   // k-offset
    const int e = ebase + m;
    f16_t* xrow = xbuf + m * 128;
    if (e < E) {
      int si = src[e], di = dst[e];
      si = ((unsigned)si < (unsigned)nrows) ? si : 0;
      di = ((unsigned)di < (unsigned)nrows) ? di : 0;
      if (use_hf) {
        const f16_t* hs = hf + (long long)si * 128 + kq;
        const f16_t* hd = hf + (long long)di * 128 + kq;
#pragma unroll
        for (int i = 0; i < 4; ++i) {
          f16x8 a = *(const f16x8*)(hs + i * 8);
          f16x8 c = *(const f16x8*)(hd + i * 8);
          f16x8 v = a * c;  // v_pk_mul_f16
          const int g = (((kq >> 3) + i) ^ m) & 15;
          *(f16x8*)(xrow + g * 8) = v;
        }
      } else {
        const float* hs = h + (long long)si * 128 + kq;
        const float* hd = h + (long long)di * 128 + kq;
#pragma unroll
        for (int i = 0; i < 4; ++i) {
          const float4 a0 = *(const float4*)(hs + i * 8);
          const float4 a1 = *(const float4*)(hs + i * 8 + 4);
          const float4 c0 = *(const float4*)(hd + i * 8);
          const float4 c1 = *(const float4*)(hd + i * 8 + 4);
          union { f16x8 v8; f16x2 v2[4]; } u;
          u.v2[0] = pk2(a0.x * c0.x, a0.y * c0.y);
          u.v2[1] = pk2(a0.z * c0.z, a0.w * c0.w);
          u.v2[2] = pk2(a1.x * c1.x, a1.y * c1.y);
          u.v2[3] = pk2(a1.z * c1.z, a1.w * c1.w);
          const int g = (((kq >> 3) + i) ^ m) & 15;
          *(f16x8*)(xrow + g * 8) = u.v8;
        }
      }
    } else {
      f16x8 z = {};
#pragma unroll
      for (int i = 0; i < 4; ++i) {
        const int g = (((kq >> 3) + i) ^ m) & 15;
        *(f16x8*)(xrow + g * 8) = z;
      }
    }
  }
  __syncthreads();  // b1: x0 ready

  const int lane = t & 63;
  const int wave = t >> 6;
  const int wf = wave & 3;   // feat-row: 64 feats
  const int ec = wave >> 2;  // edge-col: 64 edges
  const int ln = lane & 31;
  const int hi = lane >> 5;  // 0/1
  const int featBase = wf * 64;
  int e01[2];
  e01[0] = ec * 64 + ln;
  e01[1] = ec * 64 + 32 + ln;

  // ---------- GEMM1: K=128, weights direct from global (frag-linear) ----------
  const f16_t* wb1 = wks + (wf * 128 + lane) * 8;
  f32x16 acc[2][2];
#pragma unroll
  for (int mt = 0; mt < 2; ++mt)
#pragma unroll
    for (int et = 0; et < 2; ++et) acc[mt][et] = (f32x16){};

#pragma unroll
  for (int kc = 0; kc < 4; ++kc) {
#pragma unroll
    for (int ksp = 0; ksp < 2; ++ksp) {
      const int ks = kc * 2 + ksp;
      f16x8 af0 = *(const f16x8*)(wb1 + ks * 4096);
      f16x8 af1 = *(const f16x8*)(wb1 + ks * 4096 + 512);
      const int g = kc * 4 + ksp * 2 + hi;
      f16x8 bf0 = *(const f16x8*)(xbuf + e01[0] * 128 + ((g ^ e01[0]) & 15) * 8);
      f16x8 bf1 = *(const f16x8*)(xbuf + e01[1] * 128 + ((g ^ e01[1]) & 15) * 8);
      acc[0][0] = __builtin_amdgcn_mfma_f32_32x32x16_f16(af0, bf0, acc[0][0], 0, 0, 0);
      acc[0][1] = __builtin_amdgcn_mfma_f32_32x32x16_f16(af0, bf1, acc[0][1], 0, 0, 0);
      acc[1][0] = __builtin_amdgcn_mfma_f32_32x32x16_f16(af1, bf0, acc[1][0], 0, 0, 0);
      acc[1][1] = __builtin_amdgcn_mfma_f32_32x32x16_f16(af1, bf1, acc[1][1], 0, 0, 0);
    }
  }

  // ---------- LN1 stats: in-lane over 32 feats, 1 shuffle (xor 32) ----------
  {
    float s[2] = {0.f, 0.f}, sq[2] = {0.f, 0.f};
#pragma unroll
    for (int mt = 0; mt < 2; ++mt) {
#pragma unroll
      for (int rg = 0; rg < 4; ++rg) {
        const float4 bv = *(const float4*)(b1 + featBase + mt * 32 + hi * 4 + rg * 8);
#pragma unroll
        for (int r = 0; r < 4; ++r) {
          const float b = COMP(bv, r);
          const int reg = rg * 4 + r;  // row = r + 8*rg + 4*hi
#pragma unroll
          for (int et = 0; et < 2; ++et) {
            float v = acc[mt][et][reg] + b;
            acc[mt][et][reg] = v;
            s[et] += v; sq[et] += v * v;
          }
        }
      }
    }
#pragma unroll
    for (int et = 0; et < 2; ++et) {
      s[et] += __shfl_xor(s[et], 32, 64);
      sq[et] += __shfl_xor(sq[et], 32, 64);
    }
    if (hi == 0) {
#pragma unroll
      for (int et = 0; et < 2; ++et) {
        s1sum[wf * 128 + e01[et]] = s[et];
        s1sq[wf * 128 + e01[et]] = sq[et];
      }
    }
  }
  __syncthreads();  // b2: stats written; all GEMM1 x0 reads done

  // per-thread mean/rstd (no extra barrier/reduce step)
  float mu[2], rs[2];
#pragma unroll
  for (int et = 0; et < 2; ++et) {
    const int e = e01[et];
    float s = s1sum[e] + s1sum[128 + e] + s1sum[256 + e] + s1sum[384 + e];
    float sq = s1sq[e] + s1sq[128 + e] + s1sq[256 + e] + s1sq[384 + e];
    mu[et] = s * (1.f / 256.f);
    rs[et] = rsqrtf(sq * (1.f / 256.f) - mu[et] * mu[et] + 1e-5f);
  }

  // ---------- LN1 normalize + ReLU -> hv regs ----------
  f16x4 hv[2][2][4];  // [mt][et][rg]
#pragma unroll
  for (int mt = 0; mt < 2; ++mt) {
#pragma unroll
    for (int rg = 0; rg < 4; ++rg) {
      const float4 gv = *(const float4*)(g1 + featBase + mt * 32 + hi * 4 + rg * 8);
      const float4 bev = *(const float4*)(be1 + featBase + mt * 32 + hi * 4 + rg * 8);
#pragma unroll
      for (int et = 0; et < 2; ++et) {
        const int rb = rg * 4;
        float v0 = fmaxf((acc[mt][et][rb + 0] - mu[et]) * rs[et] * gv.x + bev.x, 0.f);
        float v1 = fmaxf((acc[mt][et][rb + 1] - mu[et]) * rs[et] * gv.y + bev.y, 0.f);
        float v2 = fmaxf((acc[mt][et][rb + 2] - mu[et]) * rs[et] * gv.z + bev.z, 0.f);
        float v3 = fmaxf((acc[mt][et][rb + 3] - mu[et]) * rs[et] * gv.w + bev.w, 0.f);
        union { f16x4 v4; f16x2 v2p[2]; } u;
        u.v2p[0] = pk2(v0, v1); u.v2p[1] = pk2(v2, v3);
        hv[mt][et][rg] = u.v4;
      }
    }
  }
  __syncthreads();  // b3: stats consumed everywhere; xbuf fully writable

  // x1 write: [edge][256 feats], swizzled; lane's 4 contig feats at k = fBase+mt*32+rg*8+hi*4
  {
    const int j0 = hi * 4;
#pragma unroll
    for (int mt = 0; mt < 2; ++mt) {
#pragma unroll
      for (int rg = 0; rg < 4; ++rg) {
        const int g = wf * 8 + mt * 4 + rg;  // feat 16B-group 0..31
#pragma unroll
        for (int et = 0; et < 2; ++et) {
          const int e = e01[et];
          const int gp = (g & 16) | ((g ^ e) & 15);
          *(f16x4*)(xbuf + e * 256 + gp * 8 + j0) = hv[mt][et][rg];
        }
      }
    }
  }
  __syncthreads();  // b4: x1 visible

  // ---------- GEMM2: K=256 ----------
  const f16_t* wb2 = wks + 32768 + (wf * 128 + lane) * 8;
  f32x16 acc2[2][2];
#pragma unroll
  for (int mt = 0; mt < 2; ++mt)
#pragma unroll
    for (int et = 0; et < 2; ++et) acc2[mt][et] = (f32x16){};

#pragma unroll
  for (int kc = 0; kc < 8; ++kc) {
#pragma unroll
    for (int ksp = 0; ksp < 2; ++ksp) {
      const int ks = kc * 2 + ksp;
      f16x8 af0 = *(const f16x8*)(wb2 + ks * 4096);
      f16x8 af1 = *(const f16x8*)(wb2 + ks * 4096 + 512);
      const int g = kc * 4 + ksp * 2 + hi;  // 0..31
      const int gp0 = (g & 16) | ((g ^ e01[0]) & 15);
      const int gp1 = (g & 16) | ((g ^ e01[1]) & 15);
      f16x8 bf0 = *(const f16x8*)(xbuf + e01[0] * 256 + gp0 * 8);
      f16x8 bf1 = *(const f16x8*)(xbuf + e01[1] * 256 + gp1 * 8);
      acc2[0][0] = __builtin_amdgcn_mfma_f32_32x32x16_f16(af0, bf0, acc2[0][0], 0, 0, 0);
      acc2[0][1] = __builtin_amdgcn_mfma_f32_32x32x16_f16(af0, bf1, acc2[0][1], 0, 0, 0);
      acc2[1][0] = __builtin_amdgcn_mfma_f32_32x32x16_f16(af1, bf0, acc2[1][0], 0, 0, 0);
      acc2[1][1] = __builtin_amdgcn_mfma_f32_32x32x16_f16(af1, bf1, acc2[1][1], 0, 0, 0);
    }
  }
  __syncthreads();  // b5: all x1 reads done; base stats region writable

  // ---------- LN2 stats ----------
  {
    float s[2] = {0.f, 0.f}, sq[2] = {0.f, 0.f};
#pragma unroll
    for (int mt = 0; mt < 2; ++mt) {
#pragma unroll
      for (int rg = 0; rg < 4; ++rg) {
        const float4 bv = *(const float4*)(b2 + featBase + mt * 32 + hi * 4 + rg * 8);
#pragma unroll
        for (int r = 0; r < 4; ++r) {
          const float b = COMP(bv, r);
          const int reg = rg * 4 + r;
#pragma unroll
          for (int et = 0; et < 2; ++et) {
            float v = acc2[mt][et][reg] + b;
            acc2[mt][et][reg] = v;
            s[et] += v; sq[et] += v * v;
          }
        }
      }
    }
#pragma unroll
    for (int et = 0; et < 2; ++et) {
      s[et] += __shfl_xor(s[et], 32, 64);
      sq[et] += __shfl_xor(sq[et], 32, 64);
    }
    if (hi == 0) {
#pragma unroll
      for (int et = 0; et < 2; ++et) {
        s2sum[wf * 128 + e01[et]] = s[et];
        s2sq[wf * 128 + e01[et]] = sq[et];
      }
    }
  }
  __syncthreads();  // b6: LN2 stats ready

#pragma unroll
  for (int et = 0; et < 2; ++et) {
    const int e = e01[et];
    float s = s2sum[e] + s2sum[128 + e] + s2sum[256 + e] + s2sum[384 + e];
    float sq = s2sq[e] + s2sq[128 + e] + s2sq[256 + e] + s2sq[384 + e];
    mu[et] = s * (1.f / 256.f);
    rs[et] = rsqrtf(sq * (1.f / 256.f) - mu[et] * mu[et] + 1e-5f);
  }

  // ---------- LN2 normalize + ReLU + dot(W3) ----------
  {
    float p[2] = {0.f, 0.f};
#pragma unroll
    for (int mt = 0; mt < 2; ++mt) {
#pragma unroll
      for (int rg = 0; rg < 4; ++rg) {
        const float4 gv = *(const float4*)(g2 + featBase + mt * 32 + hi * 4 + rg * 8);
        const float4 bev = *(const float4*)(be2 + featBase + mt * 32 + hi * 4 + rg * 8);
        const float4 wv = *(const float4*)(w3 + featBase + mt * 32 + hi * 4 + rg * 8);
#pragma unroll
        for (int r = 0; r < 4; ++r) {
          const float gr = COMP(gv, r), ber = COMP(bev, r), wr = COMP(wv, r);
          const int reg = rg * 4 + r;
#pragma unroll
          for (int et = 0; et < 2; ++et) {
            float v = fmaxf((acc2[mt][et][reg] - mu[et]) * rs[et] * gr + ber, 0.f);
            p[et] = fmaf(v, wr, p[et]);
          }
        }
      }
    }
#pragma unroll
    for (int et = 0; et < 2; ++et) p[et] += __shfl_xor(p[et], 32, 64);
    if (hi == 0) {
#pragma unroll
      for (int et = 0; et < 2; ++et) pbuf[wf * 128 + e01[et]] = p[et];  // disjoint region
    }
  }
  __syncthreads();  // b7
  if (t < 128) {
    int e = ebase + t;
    if (e < E) {
      float sres = pbuf[t] + pbuf[128 + t] + pbuf[256 + t] + pbuf[384 + t] + b3[0];
      out[e] = 1.f / (1.f + __expf(-sres));
    }
  }
}

extern "C" void kernel_launch(void* const* d_in, const int* in_sizes, int n_in,
                              void* d_out, int out_size, void* d_ws, size_t ws_size,
                              hipStream_t stream) {
  const float* h = (const float*)d_in[0];
  const int* src = (const int*)d_in[1];
  const int* dst = (const int*)d_in[2];
  const float* W1 = (const float*)d_in[3];
  const float* b1 = (const float*)d_in[4];
  const float* g1 = (const float*)d_in[5];
  const float* be1 = (const float*)d_in[6];
  const float* W2 = (const float*)d_in[7];
  const float* b2 = (const float*)d_in[8];
  const float* g2 = (const float*)d_in[9];
  const float* be2 = (const float*)d_in[10];
  const float* W3 = (const float*)d_in[11];
  const float* b3 = (const float*)d_in[12];
  float* out = (float*)d_out;
  const int E = in_sizes[1];
  const int nh = in_sizes[0];        // nrows * 128
  const int nrows = nh / 128;
  f16_t* wks = (f16_t*)d_ws;         // weights: 98304 f16 = 196608 B
  f16_t* hfp = wks + 98304;          // h in fp16: nh * 2 B
  const size_t need = 196608 + (size_t)nh * 2;
  const int use_hf = (ws_size >= need) ? 1 : 0;

  wconv<<<256, 256, 0, stream>>>(W1, W2, wks);
  if (use_hf) {
    const int n8 = nh / 8;
    hconv<<<(n8 + 255) / 256, 256, 0, stream>>>(h, hfp, n8);
  }
  const int tiles = (E + 127) / 128;
  fused_mlp<<<tiles, 512, 0, stream>>>(h, hfp, use_hf, src, dst, wks,
                                       b1, g1, be1, b2, g2, be2, W3, b3,
                                       out, E, nrows);
}

// Round 11
// 303.549 us; speedup vs baseline: 1.0433x; 1.0433x over previous
//
#include <hip/hip_runtime.h>
#include <math.h>

typedef _Float16 f16_t;
typedef _Float16 f16x8 __attribute__((ext_vector_type(8)));
typedef _Float16 f16x4 __attribute__((ext_vector_type(4)));
typedef _Float16 f16x2 __attribute__((ext_vector_type(2)));
typedef __fp16 h16x2 __attribute__((ext_vector_type(2)));
typedef float f32x4 __attribute__((ext_vector_type(4)));

// fp32 -> fp16 weights in 16x16x32-MFMA A-fragment-linear order:
// frag element (kc, nt, lane, j) = W[nt*16 + (lane&15)][kc*32 + (lane>>4)*8 + j]
// stored at ((kc*16 + nt)*64 + lane)*8 + j.
// W1 (kc 0..3) at 0 (32768 elems); W2 (kc 0..7) at 32768 (65536 elems).
__global__ void wconv(const float* __restrict__ W1, const float* __restrict__ W2,
                      f16_t* __restrict__ o) {
  int i = blockIdx.x * 256 + threadIdx.x;  // 0..65535
  if (i < 32768) {
    int n = i >> 7, k = i & 127;
    int kc = k >> 5, q = (k >> 3) & 3, j = k & 7;
    int nt = n >> 4, c = n & 15;
    o[((kc * 16 + nt) * 64 + q * 16 + c) * 8 + j] = (f16_t)W1[i];
  }
  {
    int n = i >> 8, k = i & 255;
    int kc = k >> 5, q = (k >> 3) & 3, j = k & 7;
    int nt = n >> 4, c = n & 15;
    o[32768 + ((kc * 16 + nt) * 64 + q * 16 + c) * 8 + j] = (f16_t)W2[i];
  }
}

// h fp32 -> fp16 (8 elems/thread)
__global__ void hconv(const float* __restrict__ h, f16_t* __restrict__ hf, int n8) {
  int i = blockIdx.x * 256 + threadIdx.x;
  if (i < n8) {
    const float4 a = *(const float4*)(h + i * 8);
    const float4 b = *(const float4*)(h + i * 8 + 4);
    f16x8 v;
    v[0] = (f16_t)a.x; v[1] = (f16_t)a.y; v[2] = (f16_t)a.z; v[3] = (f16_t)a.w;
    v[4] = (f16_t)b.x; v[5] = (f16_t)b.y; v[6] = (f16_t)b.z; v[7] = (f16_t)b.w;
    *(f16x8*)(hf + i * 8) = v;
  }
}

__device__ __forceinline__ f16x2 pk2(float a, float b) {
  union { h16x2 h; f16x2 f; } u;
  u.h = __builtin_amdgcn_cvt_pkrtz(a, b);
  return u.f;
}

// Transposed fused MLP: D[feat][edge] = W @ x^T. Tile = 128 edges, 512 threads,
// 8 waves = 4 feat-rows (64 f) x 2 edge-cols (64 e); wave tile 64f x 64e,
// acc[4][4] f32x4 = 64 AGPR (compiler reuses the same AGPRs for both GEMMs:
// v9 measured VGPR=64 + AGPR=64 = 128 -> 4 waves/SIMD, 2 blocks/CU).
// All LN math in f32x4 vector ops -> v_pk_*_f32 (2x fp32 issue rate).
// Weights stream global(L2)->VGPR fragment-linear; x LDS-stationary; static 64 KB.
__global__ __launch_bounds__(512, 2) void fused_mlp(
    const float* __restrict__ h,
    const f16_t* __restrict__ hf, int use_hf,
    const int* __restrict__ src,
    const int* __restrict__ dst,
    const f16_t* __restrict__ wks,
    const float* __restrict__ b1, const float* __restrict__ g1, const float* __restrict__ be1,
    const float* __restrict__ b2, const float* __restrict__ g2, const float* __restrict__ be2,
    const float* __restrict__ w3, const float* __restrict__ b3,
    float* __restrict__ out, int E, int nrows) {
  __shared__ __attribute__((aligned(16))) f16_t xbuf[32768];  // 64 KB exactly
  // LN1 stats alias upper region (x0 occupies lower 32 KB only):
  float* s1sum = (float*)(xbuf + 16384);          // [4][128]
  float* s1sq  = (float*)(xbuf + 16384) + 512;    // [4][128]
  float* s1mean = (float*)(xbuf + 16384) + 1024;  // [128]
  float* s1rstd = (float*)(xbuf + 16384) + 1152;  // [128]
  // LN2 stats alias base (x1 dead after GEMM2 barrier):
  float* s2sum = (float*)xbuf;
  float* s2sq  = (float*)xbuf + 512;
  float* s2mean = (float*)xbuf + 1024;
  float* s2rstd = (float*)xbuf + 1152;

  const int t = threadIdx.x;
  const int ebase = blockIdx.x * 128;

  // ---------- gather: x0[m][k] = h[src][k]*h[dst][k], fp16, swizzled stride-128 ----------
  {
    const int m = t >> 2;          // edge 0..127
    const int kq = (t & 3) * 32;   // k-offset
    const int e = ebase + m;
    f16_t* xrow = xbuf + m * 128;
    if (e < E) {
      int si = src[e], di = dst[e];
      si = ((unsigned)si < (unsigned)nrows) ? si : 0;
      di = ((unsigned)di < (unsigned)nrows) ? di : 0;
      if (use_hf) {
        const f16_t* hs = hf + (long long)si * 128 + kq;
        const f16_t* hd = hf + (long long)di * 128 + kq;
#pragma unroll
        for (int i = 0; i < 4; ++i) {
          f16x8 a = *(const f16x8*)(hs + i * 8);
          f16x8 c = *(const f16x8*)(hd + i * 8);
          f16x8 v = a * c;  // v_pk_mul_f16
          const int g = (((kq >> 3) + i) ^ m) & 15;
          *(f16x8*)(xrow + g * 8) = v;
        }
      } else {
        const float* hs = h + (long long)si * 128 + kq;
        const float* hd = h + (long long)di * 128 + kq;
#pragma unroll
        for (int i = 0; i < 4; ++i) {
          const float4 a0 = *(const float4*)(hs + i * 8);
          const float4 a1 = *(const float4*)(hs + i * 8 + 4);
          const float4 c0 = *(const float4*)(hd + i * 8);
          const float4 c1 = *(const float4*)(hd + i * 8 + 4);
          union { f16x8 v8; f16x2 v2[4]; } u;
          u.v2[0] = pk2(a0.x * c0.x, a0.y * c0.y);
          u.v2[1] = pk2(a0.z * c0.z, a0.w * c0.w);
          u.v2[2] = pk2(a1.x * c1.x, a1.y * c1.y);
          u.v2[3] = pk2(a1.z * c1.z, a1.w * c1.w);
          const int g = (((kq >> 3) + i) ^ m) & 15;
          *(f16x8*)(xrow + g * 8) = u.v8;
        }
      }
    } else {
      f16x8 z = {};
#pragma unroll
      for (int i = 0; i < 4; ++i) {
        const int g = (((kq >> 3) + i) ^ m) & 15;
        *(f16x8*)(xrow + g * 8) = z;
      }
    }
  }
  __syncthreads();  // b1: x0 ready

  const int lane = t & 63;
  const int wave = t >> 6;
  const int wf = wave & 3;   // feat-row: 64 feats
  const int ec = wave >> 2;  // edge-col: 64 edges
  const int c = lane & 15;
  const int q = lane >> 4;
  const int featBase = wf * 64;
  int eidx[4];
#pragma unroll
  for (int n = 0; n < 4; ++n) eidx[n] = ec * 64 + n * 16 + c;

  // ---------- GEMM1: K=128, weights direct from global (coalesced frags) ----------
  const f16_t* wb1 = wks + (wf * 256 + lane) * 8;
  f32x4 acc[4][4];
#pragma unroll
  for (int msf = 0; msf < 4; ++msf)
#pragma unroll
    for (int n = 0; n < 4; ++n) acc[msf][n] = (f32x4){0.f, 0.f, 0.f, 0.f};

#pragma unroll 2
  for (int kc = 0; kc < 4; ++kc) {
    f16x8 af[4], bf[4];
#pragma unroll
    for (int msf = 0; msf < 4; ++msf)
      af[msf] = *(const f16x8*)(wb1 + kc * 8192 + msf * 512);
    const int gp = ((kc * 4 + q) ^ c) & 15;
#pragma unroll
    for (int n = 0; n < 4; ++n)
      bf[n] = *(const f16x8*)(xbuf + eidx[n] * 128 + gp * 8);
#pragma unroll
    for (int msf = 0; msf < 4; ++msf)
#pragma unroll
      for (int n = 0; n < 4; ++n)
        acc[msf][n] = __builtin_amdgcn_mfma_f32_16x16x32_f16(af[msf], bf[n], acc[msf][n], 0, 0, 0);
  }

  // ---------- LN1 stats (vector f32x4 math -> v_pk ops) ----------
  {
    f32x4 s4[4], q4[4];
#pragma unroll
    for (int n = 0; n < 4; ++n) { s4[n] = (f32x4){0.f, 0.f, 0.f, 0.f}; q4[n] = s4[n]; }
#pragma unroll
    for (int msf = 0; msf < 4; ++msf) {
      const f32x4 bv = *(const f32x4*)(b1 + featBase + msf * 16 + q * 4);
#pragma unroll
      for (int n = 0; n < 4; ++n) {
        f32x4 v = acc[msf][n] + bv;
        acc[msf][n] = v;
        s4[n] += v;
        q4[n] += v * v;
      }
    }
#pragma unroll
    for (int n = 0; n < 4; ++n) {
      float s = s4[n][0] + s4[n][1] + s4[n][2] + s4[n][3];
      float sq = q4[n][0] + q4[n][1] + q4[n][2] + q4[n][3];
      s += __shfl_xor(s, 16, 64);  s += __shfl_xor(s, 32, 64);
      sq += __shfl_xor(sq, 16, 64); sq += __shfl_xor(sq, 32, 64);
      if (q == 0) {
        s1sum[wf * 128 + eidx[n]] = s;
        s1sq[wf * 128 + eidx[n]] = sq;
      }
    }
  }
  __syncthreads();  // b2: stats written; all GEMM1 x0 reads done
  if (t < 128) {
    float s = s1sum[t] + s1sum[128 + t] + s1sum[256 + t] + s1sum[384 + t];
    float sq = s1sq[t] + s1sq[128 + t] + s1sq[256 + t] + s1sq[384 + t];
    float mu = s * (1.f / 256.f);
    float var = sq * (1.f / 256.f) - mu * mu;
    s1mean[t] = mu;
    s1rstd[t] = rsqrtf(var + 1e-5f);
  }
  __syncthreads();  // b3: mean/rstd ready

  // ---------- LN1 normalize + ReLU -> hv regs (vector math) ----------
  f16x4 hv[4][4];
  {
    float mu[4], rs[4];
#pragma unroll
    for (int n = 0; n < 4; ++n) { mu[n] = s1mean[eidx[n]]; rs[n] = s1rstd[eidx[n]]; }
    const f32x4 z4 = (f32x4){0.f, 0.f, 0.f, 0.f};
#pragma unroll
    for (int msf = 0; msf < 4; ++msf) {
      const f32x4 gv = *(const f32x4*)(g1 + featBase + msf * 16 + q * 4);
      const f32x4 bev = *(const f32x4*)(be1 + featBase + msf * 16 + q * 4);
#pragma unroll
      for (int n = 0; n < 4; ++n) {
        const f32x4 a4 = gv * rs[n];
        f32x4 v = (acc[msf][n] - mu[n]) * a4 + bev;
        v = __builtin_elementwise_max(v, z4);
        union { f16x4 v4; f16x2 v2p[2]; } u;
        u.v2p[0] = pk2(v[0], v[1]); u.v2p[1] = pk2(v[2], v[3]);
        hv[msf][n] = u.v4;
      }
    }
  }
  __syncthreads();  // b4: stats consumed everywhere; xbuf fully writable
  {
    const int j0 = (q & 1) * 4;
#pragma unroll
    for (int msf = 0; msf < 4; ++msf) {
      const int g = wf * 8 + msf * 2 + (q >> 1);  // feat 16B-group 0..31
      const int gp = (g & 16) | ((g ^ c) & 15);
#pragma unroll
      for (int n = 0; n < 4; ++n)
        *(f16x4*)(xbuf + eidx[n] * 256 + gp * 8 + j0) = hv[msf][n];
    }
  }
  __syncthreads();  // b5: x1 visible

  // ---------- GEMM2: K=256, weights direct from global ----------
  const f16_t* wb2 = wks + 32768 + (wf * 256 + lane) * 8;
  f32x4 acc2[4][4];
#pragma unroll
  for (int msf = 0; msf < 4; ++msf)
#pragma unroll
    for (int n = 0; n < 4; ++n) acc2[msf][n] = (f32x4){0.f, 0.f, 0.f, 0.f};

#pragma unroll 2
  for (int kc = 0; kc < 8; ++kc) {
    f16x8 af[4], bf[4];
#pragma unroll
    for (int msf = 0; msf < 4; ++msf)
      af[msf] = *(const f16x8*)(wb2 + kc * 8192 + msf * 512);
    const int g = kc * 4 + q;  // 0..31
    const int gp = (g & 16) | ((g ^ c) & 15);
#pragma unroll
    for (int n = 0; n < 4; ++n)
      bf[n] = *(const f16x8*)(xbuf + eidx[n] * 256 + gp * 8);
#pragma unroll
    for (int msf = 0; msf < 4; ++msf)
#pragma unroll
      for (int n = 0; n < 4; ++n)
        acc2[msf][n] = __builtin_amdgcn_mfma_f32_16x16x32_f16(af[msf], bf[n], acc2[msf][n], 0, 0, 0);
  }
  __syncthreads();  // b6: all x1 reads done; base stats region writable

  // ---------- LN2 stats (vector math) ----------
  {
    f32x4 s4[4], q4[4];
#pragma unroll
    for (int n = 0; n < 4; ++n) { s4[n] = (f32x4){0.f, 0.f, 0.f, 0.f}; q4[n] = s4[n]; }
#pragma unroll
    for (int msf = 0; msf < 4; ++msf) {
      const f32x4 bv = *(const f32x4*)(b2 + featBase + msf * 16 + q * 4);
#pragma unroll
      for (int n = 0; n < 4; ++n) {
        f32x4 v = acc2[msf][n] + bv;
        acc2[msf][n] = v;
        s4[n] += v;
        q4[n] += v * v;
      }
    }
#pragma unroll
    for (int n = 0; n < 4; ++n) {
      float s = s4[n][0] + s4[n][1] + s4[n][2] + s4[n][3];
      float sq = q4[n][0] + q4[n][1] + q4[n][2] + q4[n][3];
      s += __shfl_xor(s, 16, 64);  s += __shfl_xor(s, 32, 64);
      sq += __shfl_xor(sq, 16, 64); sq += __shfl_xor(sq, 32, 64);
      if (q == 0) {
        s2sum[wf * 128 + eidx[n]] = s;
        s2sq[wf * 128 + eidx[n]] = sq;
      }
    }
  }
  __syncthreads();  // b7
  if (t < 128) {
    float s = s2sum[t] + s2sum[128 + t] + s2sum[256 + t] + s2sum[384 + t];
    float sq = s2sq[t] + s2sq[128 + t] + s2sq[256 + t] + s2sq[384 + t];
    float mu = s * (1.f / 256.f);
    float var = sq * (1.f / 256.f) - mu * mu;
    s2mean[t] = mu;
    s2rstd[t] = rsqrtf(var + 1e-5f);
  }
  __syncthreads();  // b8

  // ---------- LN2 normalize + ReLU + dot(W3) (vector math) ----------
  {
    float mu[4], rs[4];
    f32x4 p4[4];
#pragma unroll
    for (int n = 0; n < 4; ++n) {
      mu[n] = s2mean[eidx[n]]; rs[n] = s2rstd[eidx[n]];
      p4[n] = (f32x4){0.f, 0.f, 0.f, 0.f};
    }
    const f32x4 z4 = (f32x4){0.f, 0.f, 0.f, 0.f};
#pragma unroll
    for (int msf = 0; msf < 4; ++msf) {
      const f32x4 gv = *(const f32x4*)(g2 + featBase + msf * 16 + q * 4);
      const f32x4 bev = *(const f32x4*)(be2 + featBase + msf * 16 + q * 4);
      const f32x4 wv = *(const f32x4*)(w3 + featBase + msf * 16 + q * 4);
#pragma unroll
      for (int n = 0; n < 4; ++n) {
        const f32x4 a4 = gv * rs[n];
        f32x4 v = (acc2[msf][n] - mu[n]) * a4 + bev;
        v = __builtin_elementwise_max(v, z4);
        p4[n] += v * wv;
      }
    }
#pragma unroll
    for (int n = 0; n < 4; ++n) {
      float p = p4[n][0] + p4[n][1] + p4[n][2] + p4[n][3];
      p += __shfl_xor(p, 16, 64);
      p += __shfl_xor(p, 32, 64);
      if (q == 0) s2sum[wf * 128 + eidx[n]] = p;  // disjoint from s2mean/s2rstd
    }
  }
  __syncthreads();  // b9
  if (t < 128) {
    int e = ebase + t;
    if (e < E) {
      float sres = s2sum[t] + s2sum[128 + t] + s2sum[256 + t] + s2sum[384 + t] + b3[0];
      out[e] = 1.f / (1.f + __expf(-sres));
    }
  }
}

extern "C" void kernel_launch(void* const* d_in, const int* in_sizes, int n_in,
                              void* d_out, int out_size, void* d_ws, size_t ws_size,
                              hipStream_t stream) {
  const float* h = (const float*)d_in[0];
  const int* src = (const int*)d_in[1];
  const int* dst = (const int*)d_in[2];
  const float* W1 = (const float*)d_in[3];
  const float* b1 = (const float*)d_in[4];
  const float* g1 = (const float*)d_in[5];
  const float* be1 = (const float*)d_in[6];
  const float* W2 = (const float*)d_in[7];
  const float* b2 = (const float*)d_in[8];
  const float* g2 = (const float*)d_in[9];
  const float* be2 = (const float*)d_in[10];
  const float* W3 = (const float*)d_in[11];
  const float* b3 = (const float*)d_in[12];
  float* out = (float*)d_out;
  const int E = in_sizes[1];
  const int nh = in_sizes[0];        // nrows * 128
  const int nrows = nh / 128;
  f16_t* wks = (f16_t*)d_ws;         // weights: 98304 f16 = 196608 B
  f16_t* hfp = wks + 98304;          // h in fp16: nh * 2 B
  const size_t need = 196608 + (size_t)nh * 2;
  const int use_hf = (ws_size >= need) ? 1 : 0;

  wconv<<<256, 256, 0, stream>>>(W1, W2, wks);
  if (use_hf) {
    const int n8 = nh / 8;
    hconv<<<(n8 + 255) / 256, 256, 0, stream>>>(h, hfp, n8);
  }
  const int tiles = (E + 127) / 128;
  fused_mlp<<<tiles, 512, 0, stream>>>(h, hfp, use_hf, src, dst, wks,
                                       b1, g1, be1, b2, g2, be2, W3, b3,
                                       out, E, nrows);
}